// Round 4
// baseline (1059.042 us; speedup 1.0000x reference)
//
#include <hip/hip_runtime.h>
#include <hip/hip_fp16.h>
#include <stdint.h>

#define BB 256
#define TT 511
#define VV 128
#define HH 256
#define G4 1024   // 4*H

typedef _Float16 h2_t __attribute__((ext_vector_type(2)));

__device__ __forceinline__ float fdot2(uint32_t a, uint32_t b, float c) {
  return __builtin_amdgcn_fdot2(__builtin_bit_cast(h2_t, a),
                                __builtin_bit_cast(h2_t, b), c, false);
}

__device__ __forceinline__ uint32_t pack2(float a, float b) {
  __half ha = __float2half(a), hb = __float2half(b);
  return (uint32_t)__half_as_ushort(ha) | ((uint32_t)__half_as_ushort(hb) << 16);
}

// Gate-interleaved permutation: permuted col p = 4*q + m  <->  actual col q + 256*m.
// Thread q then owns the (i,f,g,o) quadruple of output q as 4 contiguous cols.

// ---------------- prep kernels (all write PERMUTED layouts) ----------------

__global__ __launch_bounds__(1024) void prep_ctx_k(
    const int* __restrict__ rhythm, const int* __restrict__ meter, const int* __restrict__ keyi,
    const float* __restrict__ er, const float* __restrict__ em, const float* __restrict__ ek,
    const float* __restrict__ W, const float* __restrict__ bias, float* __restrict__ ctxW) {
  int b = blockIdx.x, p = threadIdx.x;
  int c = (p >> 2) + 256 * (p & 3);
  int r = rhythm[b], m = meter[b], k = keyi[b];
  float acc = bias[c];
#pragma unroll
  for (int e = 0; e < 16; e++) acc += er[r*16+e] * W[(0+e)*G4 + c];
#pragma unroll
  for (int e = 0; e < 16; e++) acc += em[m*16+e] * W[(16+e)*G4 + c];
#pragma unroll
  for (int e = 0; e < 16; e++) acc += ek[k*16+e] * W[(32+e)*G4 + c];
  ctxW[b*G4 + p] = acc;
}

__global__ __launch_bounds__(1024) void prep_tune_k(
    const float* __restrict__ et, const float* __restrict__ W, float* __restrict__ tuneW) {
  int v = blockIdx.x, p = threadIdx.x;
  int c = (p >> 2) + 256 * (p & 3);
  float acc = 0.f;
#pragma unroll
  for (int e = 0; e < 32; e++) acc += et[v*32+e] * W[(48+e)*G4 + c];
  tuneW[v*G4 + p] = acc;
}

__global__ __launch_bounds__(1024) void prep_U_k(
    const float* __restrict__ U, uint32_t* __restrict__ Up) {
  int kk = blockIdx.x, p = threadIdx.x;   // kk in [0,128): packed k-pair index
  int c = (p >> 2) + 256 * (p & 3);
  Up[kk*G4 + p] = pack2(U[(2*kk)*G4 + c], U[(2*kk+1)*G4 + c]);
}

__global__ __launch_bounds__(128) void prep_Wd_k(
    const float* __restrict__ Wd, uint32_t* __restrict__ Wdp) {
  int kp = blockIdx.x, v = threadIdx.x;   // kp in [0,128)
  Wdp[kp*VV + v] = pack2(Wd[(2*kp)*VV + v], Wd[(2*kp+1)*VV + v]);
}

// ---------------- recurrent kernel ----------------
// 2-way K-split: waves 0-3 (group 0) own kp 0..63, waves 4-7 own kp 64..127.
// Thread q of each group owns permuted cols 4q..4q+3 = gates (i,f,g,o) of
// output q -> epilogue is fully parallel and redundant across groups.
// Per group: KREG=50 kp in VGPRs (200 regs/thread), KLDS=14 kp in LDS.
// h broadcast: lane-spread ds_read_b32 of own group's hbuf slice + v_readlane.

#define NT 512
#define KREG 50
#define KLDS 14
// u32 layout: Ulds[2*14*1024] | zpart[2*1024 f32] | hbuf[128] | tlds[511]
#define OFF_ZPART (2*KLDS*G4)
#define OFF_HBUF  (OFF_ZPART + 2*G4)
#define OFF_TLDS  (OFF_HBUF + 128)
#define SMEM_U32  (OFF_TLDS + TT + 1)
#define SMEM_BYTES (SMEM_U32*4)   // ~125.4 KB

__global__ __launch_bounds__(NT, 2) void lstm_rec_k(
    const int* __restrict__ tune, const int* __restrict__ tlen,
    const uint32_t* __restrict__ Up, const float* __restrict__ ctxW,
    const float* __restrict__ tuneW, __half* __restrict__ h_hist) {
  extern __shared__ uint32_t smem[];
  uint32_t* Ulds  = smem;
  float*    zpart = (float*)(smem + OFF_ZPART);
  uint32_t* hbuf  = smem + OFF_HBUF;
  int*      tlds  = (int*)(smem + OFF_TLDS);

  int b    = blockIdx.x;
  int tid  = threadIdx.x;
  int g    = tid >> 8;        // K-group (0/1)
  int q    = tid & 255;       // output-owner index
  int lane = tid & 63;
  int L    = tlen[b];

  for (int i = tid; i < TT; i += NT) tlds[i] = tune[b*TT + i];
  if (tid < 128) hbuf[tid] = 0u;
  for (int idx = tid; idx < 2*KLDS*G4; idx += NT) {
    int row = idx >> 10, p = idx & 1023;
    int gg = row / KLDS, r = row % KLDS;
    Ulds[idx] = Up[(gg*64 + KREG + r)*G4 + p];
  }

  uint4 ureg[KREG];
  {
    const uint32_t* ubase = Up + (size_t)(g*64)*G4 + 4*q;
#pragma unroll
    for (int kk = 0; kk < KREG; kk++) ureg[kk] = *(const uint4*)(ubase + (size_t)kk*G4);
  }
  float4 ctxv = *(const float4*)(ctxW + (size_t)b*G4 + 4*q);
  float cc = 0.f;
  __syncthreads();

  const uint32_t* uldsrow = Ulds + (size_t)(g*KLDS)*G4 + 4*q;
  bool owner = ((q >> 7) == g);           // this thread publishes h_q (wave-uniform)
  __half* hh_base = h_hist + (size_t)b*TT*HH + q;

  for (int t = 0; t < L; t++) {
    uint32_t vh = hbuf[g*64 + lane];      // own group's packed-h slice, lane-spread
    int v = tlds[t];
    float4 tw = *(const float4*)(tuneW + (size_t)v*G4 + 4*q);   // issued early

    float a0e = 0.f, a1e = 0.f, a2e = 0.f, a3e = 0.f;
    float a0o = 0.f, a1o = 0.f, a2o = 0.f, a3o = 0.f;
#pragma unroll
    for (int kk = 0; kk < KREG; kk += 2) {
      uint32_t hs0 = (uint32_t)__builtin_amdgcn_readlane((int)vh, kk);
      uint32_t hs1 = (uint32_t)__builtin_amdgcn_readlane((int)vh, kk + 1);
      a0e = fdot2(hs0, ureg[kk].x, a0e);
      a1e = fdot2(hs0, ureg[kk].y, a1e);
      a2e = fdot2(hs0, ureg[kk].z, a2e);
      a3e = fdot2(hs0, ureg[kk].w, a3e);
      a0o = fdot2(hs1, ureg[kk+1].x, a0o);
      a1o = fdot2(hs1, ureg[kk+1].y, a1o);
      a2o = fdot2(hs1, ureg[kk+1].z, a2o);
      a3o = fdot2(hs1, ureg[kk+1].w, a3o);
    }
#pragma unroll
    for (int r = 0; r < KLDS; r += 2) {
      uint4 ua = *(const uint4*)(uldsrow + (size_t)r*G4);
      uint4 ub = *(const uint4*)(uldsrow + (size_t)(r+1)*G4);
      uint32_t hs0 = (uint32_t)__builtin_amdgcn_readlane((int)vh, KREG + r);
      uint32_t hs1 = (uint32_t)__builtin_amdgcn_readlane((int)vh, KREG + r + 1);
      a0e = fdot2(hs0, ua.x, a0e);
      a1e = fdot2(hs0, ua.y, a1e);
      a2e = fdot2(hs0, ua.z, a2e);
      a3e = fdot2(hs0, ua.w, a3e);
      a0o = fdot2(hs1, ub.x, a0o);
      a1o = fdot2(hs1, ub.y, a1o);
      a2o = fdot2(hs1, ub.z, a2o);
      a3o = fdot2(hs1, ub.w, a3o);
    }
    float s0 = a0e + a0o, s1 = a1e + a1o, s2 = a2e + a2o, s3 = a3e + a3o;
    *(float4*)(zpart + g*G4 + 4*q) = make_float4(s0, s1, s2, s3);
    __syncthreads();

    // fully parallel epilogue (redundant across the 2 groups)
    float4 zp = *(const float4*)(zpart + (1-g)*G4 + 4*q);
    float zi = s0 + zp.x + ctxv.x + tw.x;
    float zf = s1 + zp.y + ctxv.y + tw.y;
    float zg = s2 + zp.z + ctxv.z + tw.z;
    float zo = s3 + zp.w + ctxv.w + tw.w;
    float gi = 1.f / (1.f + __expf(-zi));
    float gf = 1.f / (1.f + __expf(-zf));
    float e2 = __expf(2.f*zg);
    float gg = (e2 - 1.f) / (e2 + 1.f);
    float go = 1.f / (1.f + __expf(-zo));
    cc = gf*cc + gi*gg;
    float ec = __expf(2.f*cc);
    float th = (ec - 1.f) / (ec + 1.f);
    float hv = go * th;
    if (owner) {
      __half hhv = __float2half(hv);
      ((__half*)hbuf)[q] = hhv;           // group-internal publish
      hh_base[(size_t)t*HH] = hhv;        // fire-and-forget history store
    }
    __syncthreads();
  }
}

// ---------------- output projection ----------------
// out[b,t,:] = h[b,t,:] @ Wd + bd  (t < L), else bd.
// h history lives (f16-packed) in d_out itself; each block stages its A-tile to
// LDS before overwriting exactly those rows -> no race (rows are block-private).

__global__ __launch_bounds__(256) void out_gemm_k(
    const uint32_t* __restrict__ hsrc, const uint32_t* __restrict__ Wdp,
    const float* __restrict__ bd, const int* __restrict__ tlen,
    float* __restrict__ out) {
  __shared__ uint32_t A[64][128];   // 32KB: 64 rows x 128 packed f16-pairs
  int bb = blockIdx.x;
  int b  = bb >> 3, t0 = (bb & 7) << 6;
  int tid = threadIdx.x;
  int L = tlen[b];
  for (int idx = tid; idx < 64*128; idx += 256) {
    int r = idx >> 7, kp = idx & 127;
    int t = t0 + r;
    A[r][kp] = (t < TT) ? hsrc[((size_t)b*TT + t)*128 + kp] : 0u;
  }
  __syncthreads();
  int v = tid & 127, rg = tid >> 7;
  float acc[32];
#pragma unroll
  for (int r = 0; r < 32; r++) acc[r] = 0.f;
  for (int kb = 0; kb < 4; kb++) {
    uint32_t w[32];
#pragma unroll
    for (int q = 0; q < 32; q++) w[q] = Wdp[(kb*32+q)*VV + v];
#pragma unroll
    for (int r = 0; r < 32; r++) {
      const uint32_t* ar = &A[rg*32 + r][kb*32];
#pragma unroll
      for (int q4 = 0; q4 < 8; q4++) {
        uint4 a4 = *(const uint4*)(ar + q4*4);   // wave-uniform -> broadcast
        acc[r] = fdot2(a4.x, w[4*q4+0], acc[r]);
        acc[r] = fdot2(a4.y, w[4*q4+1], acc[r]);
        acc[r] = fdot2(a4.z, w[4*q4+2], acc[r]);
        acc[r] = fdot2(a4.w, w[4*q4+3], acc[r]);
      }
    }
  }
  float bias = bd[v];
#pragma unroll
  for (int r = 0; r < 32; r++) {
    int t = t0 + rg*32 + r;
    if (t < TT) {
      out[((size_t)b*TT + t)*VV + v] = (t < L) ? (acc[r] + bias) : bias;
    }
  }
}

// ---------------- launch ----------------

extern "C" void kernel_launch(void* const* d_in, const int* in_sizes, int n_in,
                              void* d_out, int out_size, void* d_ws, size_t ws_size,
                              hipStream_t stream) {
  const int*   tune   = (const int*)d_in[0];
  const int*   rhythm = (const int*)d_in[1];
  const int*   meter  = (const int*)d_in[2];
  const int*   keyi   = (const int*)d_in[3];
  const int*   tlen   = (const int*)d_in[4];
  const float* er     = (const float*)d_in[5];
  const float* em     = (const float*)d_in[6];
  const float* ek     = (const float*)d_in[7];
  const float* et     = (const float*)d_in[8];
  const float* W      = (const float*)d_in[9];
  const float* U      = (const float*)d_in[10];
  const float* bias   = (const float*)d_in[11];
  const float* Wd     = (const float*)d_in[12];
  const float* bd     = (const float*)d_in[13];
  (void)in_sizes; (void)n_in; (void)out_size; (void)ws_size;

  char* ws = (char*)d_ws;
  uint32_t* Up    = (uint32_t*)(ws);                                      // 512KB
  float*    ctxW  = (float*)(ws + (512<<10));                             // 1MB
  float*    tuneW = (float*)(ws + (512<<10) + (1024<<10));                // 516KB
  uint32_t* Wdp   = (uint32_t*)(ws + (512<<10) + (1024<<10) + (516<<10)); // 64KB

  hipFuncSetAttribute((const void*)lstm_rec_k,
                      hipFuncAttributeMaxDynamicSharedMemorySize, SMEM_BYTES);

  prep_ctx_k <<<BB,    1024, 0, stream>>>(rhythm, meter, keyi, er, em, ek, W, bias, ctxW);
  prep_tune_k<<<VV+1,  1024, 0, stream>>>(et, W, tuneW);
  prep_U_k   <<<128,   1024, 0, stream>>>(U, Up);
  prep_Wd_k  <<<128,   VV,   0, stream>>>(Wd, Wdp);
  lstm_rec_k <<<BB, NT, SMEM_BYTES, stream>>>(tune, tlen, Up, ctxW, tuneW, (__half*)d_out);
  out_gemm_k <<<BB*8,  256,  0, stream>>>((const uint32_t*)d_out, Wdp, bd, tlen, (float*)d_out);
}

// Round 6
// 984.928 us; speedup vs baseline: 1.0752x; 1.0752x over previous
//
#include <hip/hip_runtime.h>
#include <hip/hip_fp16.h>
#include <stdint.h>

#define BB 256
#define TT 511
#define VV 128
#define HH 256
#define G4 1024   // 4*H

typedef _Float16 h2_t __attribute__((ext_vector_type(2)));

__device__ __forceinline__ float fdot2(uint32_t a, uint32_t b, float c) {
  return __builtin_amdgcn_fdot2(__builtin_bit_cast(h2_t, a),
                                __builtin_bit_cast(h2_t, b), c, false);
}

__device__ __forceinline__ uint32_t pack2(float a, float b) {
  __half ha = __float2half(a), hb = __float2half(b);
  return (uint32_t)__half_as_ushort(ha) | ((uint32_t)__half_as_ushort(hb) << 16);
}

// Gate-interleaved permutation: permuted col p = 4*q + m  <->  actual col q + 256*m.
// Thread q then owns the (i,f,g,o) quadruple of output q as 4 contiguous cols.

// ---------------- prep kernels (all write PERMUTED layouts) ----------------

__global__ __launch_bounds__(1024) void prep_ctx_k(
    const int* __restrict__ rhythm, const int* __restrict__ meter, const int* __restrict__ keyi,
    const float* __restrict__ er, const float* __restrict__ em, const float* __restrict__ ek,
    const float* __restrict__ W, const float* __restrict__ bias, float* __restrict__ ctxW) {
  int b = blockIdx.x, p = threadIdx.x;
  int c = (p >> 2) + 256 * (p & 3);
  int r = rhythm[b], m = meter[b], k = keyi[b];
  float acc = bias[c];
#pragma unroll
  for (int e = 0; e < 16; e++) acc += er[r*16+e] * W[(0+e)*G4 + c];
#pragma unroll
  for (int e = 0; e < 16; e++) acc += em[m*16+e] * W[(16+e)*G4 + c];
#pragma unroll
  for (int e = 0; e < 16; e++) acc += ek[k*16+e] * W[(32+e)*G4 + c];
  ctxW[b*G4 + p] = acc;
}

__global__ __launch_bounds__(1024) void prep_tune_k(
    const float* __restrict__ et, const float* __restrict__ W, float* __restrict__ tuneW) {
  int v = blockIdx.x, p = threadIdx.x;
  int c = (p >> 2) + 256 * (p & 3);
  float acc = 0.f;
#pragma unroll
  for (int e = 0; e < 32; e++) acc += et[v*32+e] * W[(48+e)*G4 + c];
  tuneW[v*G4 + p] = acc;
}

__global__ __launch_bounds__(1024) void prep_U_k(
    const float* __restrict__ U, uint32_t* __restrict__ Up) {
  int kk = blockIdx.x, p = threadIdx.x;   // kk in [0,128): packed k-pair index
  int c = (p >> 2) + 256 * (p & 3);
  Up[kk*G4 + p] = pack2(U[(2*kk)*G4 + c], U[(2*kk+1)*G4 + c]);
}

__global__ __launch_bounds__(128) void prep_Wd_k(
    const float* __restrict__ Wd, uint32_t* __restrict__ Wdp) {
  int kp = blockIdx.x, v = threadIdx.x;   // kp in [0,128)
  Wdp[kp*VV + v] = pack2(Wd[(2*kp)*VV + v], Wd[(2*kp+1)*VV + v]);
}

// ---------------- recurrent kernel ----------------
// 2-way K-split: waves 0-3 (group 0) own kp 0..63, waves 4-7 own kp 64..127.
// Thread q of each group owns permuted cols 4q..4q+3 = gates (i,f,g,o) of
// output q -> epilogue fully parallel (redundant across groups).
// Per group: KREG=48 kp in VGPRs (192 regs/thread), KLDS=16 kp in LDS.
// h delivered via UNIFORM ds_read_b128 of hbuf (broadcast, no readlane).
// amdgpu_waves_per_eu(2,2): LDS (dynamic, invisible to the allocator) already
// caps us at 2 waves/SIMD; pinning max=2 removes the allocator's incentive to
// split ureg into AGPRs (the accvgpr_read tax seen in rounds 1-4).

#define NT 512
#define KREG 48
#define KLDS 16
// u32 layout: Ulds[2*16*1024] | zpart[2*1024 f32] | hbuf[128] | tlds[512]
#define OFF_ZPART (2*KLDS*G4)
#define OFF_HBUF  (OFF_ZPART + 2*G4)
#define OFF_TLDS  (OFF_HBUF + 128)
#define SMEM_U32  (OFF_TLDS + TT + 1)
#define SMEM_BYTES (SMEM_U32*4)   // ~141.8 KB

__global__ __launch_bounds__(NT)
__attribute__((amdgpu_waves_per_eu(2, 2)))
void lstm_rec_k(
    const int* __restrict__ tune, const int* __restrict__ tlen,
    const uint32_t* __restrict__ Up, const float* __restrict__ ctxW,
    const float* __restrict__ tuneW, __half* __restrict__ h_hist) {
  extern __shared__ uint32_t smem[];
  uint32_t* Ulds  = smem;
  float*    zpart = (float*)(smem + OFF_ZPART);
  uint32_t* hbuf  = smem + OFF_HBUF;
  int*      tlds  = (int*)(smem + OFF_TLDS);

  int b    = blockIdx.x;
  int tid  = threadIdx.x;
  int g    = tid >> 8;        // K-group (0/1)
  int q    = tid & 255;       // output-owner index
  int L    = tlen[b];

  for (int i = tid; i < TT; i += NT) tlds[i] = tune[b*TT + i];
  if (tid < 128) hbuf[tid] = 0u;
  for (int idx = tid; idx < 2*KLDS*G4; idx += NT) {
    int row = idx >> 10, p = idx & 1023;
    int gg = row / KLDS, r = row % KLDS;
    Ulds[idx] = Up[(gg*64 + KREG + r)*G4 + p];
  }

  uint4 ureg[KREG];
  {
    const uint32_t* ubase = Up + (size_t)(g*64)*G4 + 4*q;
#pragma unroll
    for (int kk = 0; kk < KREG; kk++) ureg[kk] = *(const uint4*)(ubase + (size_t)kk*G4);
  }
  float4 ctxv = *(const float4*)(ctxW + (size_t)b*G4 + 4*q);
  float cc = 0.f;
  __syncthreads();

  const uint32_t* uldsrow = Ulds + (size_t)(g*KLDS)*G4 + 4*q;
  const uint32_t* hg = hbuf + g*64;       // own group's packed-h slice (uniform)
  bool owner = ((q >> 7) == g);           // this thread publishes h_q (wave-uniform)
  __half* hh_base = h_hist + (size_t)b*TT*HH + q;

  for (int t = 0; t < L; t++) {
    int v = tlds[t];
    float4 tw = *(const float4*)(tuneW + (size_t)v*G4 + 4*q);   // issued early

    float a0e = 0.f, a1e = 0.f, a2e = 0.f, a3e = 0.f;
    float a0o = 0.f, a1o = 0.f, a2o = 0.f, a3o = 0.f;
#pragma unroll
    for (int kq = 0; kq < KREG/4; kq++) {
      uint4 h4 = *(const uint4*)(hg + 4*kq);    // uniform b128 -> broadcast
      a0e = fdot2(h4.x, ureg[4*kq+0].x, a0e);
      a1e = fdot2(h4.x, ureg[4*kq+0].y, a1e);
      a2e = fdot2(h4.x, ureg[4*kq+0].z, a2e);
      a3e = fdot2(h4.x, ureg[4*kq+0].w, a3e);
      a0o = fdot2(h4.y, ureg[4*kq+1].x, a0o);
      a1o = fdot2(h4.y, ureg[4*kq+1].y, a1o);
      a2o = fdot2(h4.y, ureg[4*kq+1].z, a2o);
      a3o = fdot2(h4.y, ureg[4*kq+1].w, a3o);
      a0e = fdot2(h4.z, ureg[4*kq+2].x, a0e);
      a1e = fdot2(h4.z, ureg[4*kq+2].y, a1e);
      a2e = fdot2(h4.z, ureg[4*kq+2].z, a2e);
      a3e = fdot2(h4.z, ureg[4*kq+2].w, a3e);
      a0o = fdot2(h4.w, ureg[4*kq+3].x, a0o);
      a1o = fdot2(h4.w, ureg[4*kq+3].y, a1o);
      a2o = fdot2(h4.w, ureg[4*kq+3].z, a2o);
      a3o = fdot2(h4.w, ureg[4*kq+3].w, a3o);
    }
#pragma unroll
    for (int r4 = 0; r4 < KLDS/4; r4++) {
      uint4 h4 = *(const uint4*)(hg + KREG + 4*r4);
      uint4 ua = *(const uint4*)(uldsrow + (size_t)(4*r4+0)*G4);
      uint4 ub = *(const uint4*)(uldsrow + (size_t)(4*r4+1)*G4);
      uint4 uc = *(const uint4*)(uldsrow + (size_t)(4*r4+2)*G4);
      uint4 ud = *(const uint4*)(uldsrow + (size_t)(4*r4+3)*G4);
      a0e = fdot2(h4.x, ua.x, a0e);
      a1e = fdot2(h4.x, ua.y, a1e);
      a2e = fdot2(h4.x, ua.z, a2e);
      a3e = fdot2(h4.x, ua.w, a3e);
      a0o = fdot2(h4.y, ub.x, a0o);
      a1o = fdot2(h4.y, ub.y, a1o);
      a2o = fdot2(h4.y, ub.z, a2o);
      a3o = fdot2(h4.y, ub.w, a3o);
      a0e = fdot2(h4.z, uc.x, a0e);
      a1e = fdot2(h4.z, uc.y, a1e);
      a2e = fdot2(h4.z, uc.z, a2e);
      a3e = fdot2(h4.z, uc.w, a3e);
      a0o = fdot2(h4.w, ud.x, a0o);
      a1o = fdot2(h4.w, ud.y, a1o);
      a2o = fdot2(h4.w, ud.z, a2o);
      a3o = fdot2(h4.w, ud.w, a3o);
    }
    float s0 = a0e + a0o, s1 = a1e + a1o, s2 = a2e + a2o, s3 = a3e + a3o;
    *(float4*)(zpart + g*G4 + 4*q) = make_float4(s0, s1, s2, s3);
    __syncthreads();

    // fully parallel epilogue (redundant across the 2 groups)
    float4 zp = *(const float4*)(zpart + (1-g)*G4 + 4*q);
    float zi = s0 + zp.x + ctxv.x + tw.x;
    float zf = s1 + zp.y + ctxv.y + tw.y;
    float zg = s2 + zp.z + ctxv.z + tw.z;
    float zo = s3 + zp.w + ctxv.w + tw.w;
    float gi = 1.f / (1.f + __expf(-zi));
    float gf = 1.f / (1.f + __expf(-zf));
    float e2 = __expf(2.f*zg);
    float gg = (e2 - 1.f) / (e2 + 1.f);
    float go = 1.f / (1.f + __expf(-zo));
    cc = gf*cc + gi*gg;
    float ec = __expf(2.f*cc);
    float th = (ec - 1.f) / (ec + 1.f);
    float hv = go * th;
    if (owner) {
      __half hhv = __float2half(hv);
      ((__half*)hbuf)[q] = hhv;           // group-internal publish
      hh_base[(size_t)t*HH] = hhv;        // fire-and-forget history store
    }
    __syncthreads();
  }
}

// ---------------- output projection ----------------
// out[b,t,:] = h[b,t,:] @ Wd + bd  (t < L), else bd.
// h history lives (f16-packed) in d_out itself; each block stages its A-tile to
// LDS before overwriting exactly those rows -> no race (rows are block-private).

__global__ __launch_bounds__(256) void out_gemm_k(
    const uint32_t* __restrict__ hsrc, const uint32_t* __restrict__ Wdp,
    const float* __restrict__ bd, const int* __restrict__ tlen,
    float* __restrict__ out) {
  __shared__ uint32_t A[64][128];   // 32KB: 64 rows x 128 packed f16-pairs
  int bb = blockIdx.x;
  int b  = bb >> 3, t0 = (bb & 7) << 6;
  int tid = threadIdx.x;
  int L = tlen[b];
  for (int idx = tid; idx < 64*128; idx += 256) {
    int r = idx >> 7, kp = idx & 127;
    int t = t0 + r;
    A[r][kp] = (t < TT) ? hsrc[((size_t)b*TT + t)*128 + kp] : 0u;
  }
  __syncthreads();
  int v = tid & 127, rg = tid >> 7;
  float acc[32];
#pragma unroll
  for (int r = 0; r < 32; r++) acc[r] = 0.f;
  for (int kb = 0; kb < 4; kb++) {
    uint32_t w[32];
#pragma unroll
    for (int q = 0; q < 32; q++) w[q] = Wdp[(kb*32+q)*VV + v];
#pragma unroll
    for (int r = 0; r < 32; r++) {
      const uint32_t* ar = &A[rg*32 + r][kb*32];
#pragma unroll
      for (int q4 = 0; q4 < 8; q4++) {
        uint4 a4 = *(const uint4*)(ar + q4*4);   // wave-uniform -> broadcast
        acc[r] = fdot2(a4.x, w[4*q4+0], acc[r]);
        acc[r] = fdot2(a4.y, w[4*q4+1], acc[r]);
        acc[r] = fdot2(a4.z, w[4*q4+2], acc[r]);
        acc[r] = fdot2(a4.w, w[4*q4+3], acc[r]);
      }
    }
  }
  float bias = bd[v];
#pragma unroll
  for (int r = 0; r < 32; r++) {
    int t = t0 + rg*32 + r;
    if (t < TT) {
      out[((size_t)b*TT + t)*VV + v] = (t < L) ? (acc[r] + bias) : bias;
    }
  }
}

// ---------------- launch ----------------

extern "C" void kernel_launch(void* const* d_in, const int* in_sizes, int n_in,
                              void* d_out, int out_size, void* d_ws, size_t ws_size,
                              hipStream_t stream) {
  const int*   tune   = (const int*)d_in[0];
  const int*   rhythm = (const int*)d_in[1];
  const int*   meter  = (const int*)d_in[2];
  const int*   keyi   = (const int*)d_in[3];
  const int*   tlen   = (const int*)d_in[4];
  const float* er     = (const float*)d_in[5];
  const float* em     = (const float*)d_in[6];
  const float* ek     = (const float*)d_in[7];
  const float* et     = (const float*)d_in[8];
  const float* W      = (const float*)d_in[9];
  const float* U      = (const float*)d_in[10];
  const float* bias   = (const float*)d_in[11];
  const float* Wd     = (const float*)d_in[12];
  const float* bd     = (const float*)d_in[13];
  (void)in_sizes; (void)n_in; (void)out_size; (void)ws_size;

  char* ws = (char*)d_ws;
  uint32_t* Up    = (uint32_t*)(ws);                                      // 512KB
  float*    ctxW  = (float*)(ws + (512<<10));                             // 1MB
  float*    tuneW = (float*)(ws + (512<<10) + (1024<<10));                // 516KB
  uint32_t* Wdp   = (uint32_t*)(ws + (512<<10) + (1024<<10) + (516<<10)); // 64KB

  hipFuncSetAttribute((const void*)lstm_rec_k,
                      hipFuncAttributeMaxDynamicSharedMemorySize, SMEM_BYTES);

  prep_ctx_k <<<BB,    1024, 0, stream>>>(rhythm, meter, keyi, er, em, ek, W, bias, ctxW);
  prep_tune_k<<<VV+1,  1024, 0, stream>>>(et, W, tuneW);
  prep_U_k   <<<128,   1024, 0, stream>>>(U, Up);
  prep_Wd_k  <<<128,   VV,   0, stream>>>(Wd, Wdp);
  lstm_rec_k <<<BB, NT, SMEM_BYTES, stream>>>(tune, tlen, Up, ctxW, tuneW, (__half*)d_out);
  out_gemm_k <<<BB*8,  256,  0, stream>>>((const uint32_t*)d_out, Wdp, bd, tlen, (float*)d_out);
}